// Round 5
// baseline (693.997 us; speedup 1.0000x reference)
//
#include <hip/hip_runtime.h>

// Self-attention, B=4, N=4096, D=256 (single head over full D).
//   Q = x Wq^T + bq ; K,V likewise ; S = Q K^T ; mask==0 -> -inf ;
//   attn = softmax(S/16) ; out = attn V        (fp32 in/out)
// R5: R2-R4 were all ~275us regardless of structure -> latency-bound mask
//     streaming from HBM (256MB, ~2KB/wave in flight, convoying at 8% BW).
//     Fix: compress mask to 1 bit/elem in a dedicated BW-bound kernel
//     (maskc, ballot-based), flash reads the 8MB bitmask from L2/LLC.
//     Q fused into flash (frees ws for bitmask); kv computes K/V with
//     inline fp32->bf16 weight cvt (wconv deleted).
// ws: Kb bf16 8MiB | Vt bf16 8MiB | bm u64 8MiB   (= 24MiB, proven size)

#define DEV static __device__ __forceinline__

typedef __attribute__((ext_vector_type(8))) short bf8;   // 8 bf16 (4 VGPR)
typedef __attribute__((ext_vector_type(4))) float f4;
typedef unsigned long long u64;

DEV short f2bf(float x) {  // fp32 -> bf16 RNE (inputs finite)
  unsigned u = __builtin_bit_cast(unsigned, x);
  u += 0x7FFFu + ((u >> 16) & 1u);
  return (short)(u >> 16);
}

DEV bf8 cvt8(f4 a, f4 b) {
  bf8 r;
  r[0] = f2bf(a[0]); r[1] = f2bf(a[1]); r[2] = f2bf(a[2]); r[3] = f2bf(a[3]);
  r[4] = f2bf(b[0]); r[5] = f2bf(b[1]); r[6] = f2bf(b[2]); r[7] = f2bf(b[3]);
  return r;
}

DEV bf8 cvtp(const float* p) { return cvt8(*(const f4*)p, *(const f4*)(p + 4)); }

DEV f4 mfma16(bf8 a, bf8 b, f4 c) {
  return __builtin_amdgcn_mfma_f32_16x16x32_bf16(a, b, c, 0, 0, 0);
}

// LDS-only barrier (P dbuf visibility); keeps global loads in flight.
DEV void lds_barrier() {
  __asm__ __volatile__("s_waitcnt lgkmcnt(0)\ns_barrier" ::: "memory");
}

// ---------------- kernel A: mask int32 -> bitmask (1b/elem) ----------------
// bm[i] holds mask ints [64i, 64i+64), bit k = (mask[64i+k] != 0).
// 512 blocks x 256 thr = 2048 waves x 128 iters x 256 ints. Loads: 4
// stride-64 coalesced dwords/lane; ballot -> u64; lane0 stores 4 words.
__global__ void maskc(const int* __restrict__ mask, u64* __restrict__ bm) {
  const int g = (blockIdx.x * 256 + threadIdx.x) >> 6;  // global wave 0..2047
  const int lane = threadIdx.x & 63;
#pragma unroll 2
  for (int it = 0; it < 128; ++it) {
    const long base = ((long)(it * 2048 + g)) * 256;
    u64 b0 = __ballot(mask[base + lane] != 0);
    u64 b1 = __ballot(mask[base + 64 + lane] != 0);
    u64 b2 = __ballot(mask[base + 128 + lane] != 0);
    u64 b3 = __ballot(mask[base + 192 + lane] != 0);
    if (lane == 0) {
      u64* p = bm + (base >> 6);
      p[0] = b0; p[1] = b1; p[2] = b2; p[3] = b3;
    }
  }
}

// ---------------- kernel B: K,V projection ----------------
// 256 blocks x 64 rows. Both K and V per block (x read once). Weights
// loaded fp32 + inline cvt (no wconv). Wave w owns out-cols [w*64,+64).
__launch_bounds__(256, 2)
__global__ void kv(const float* __restrict__ x, const float* __restrict__ Wk,
                   const float* __restrict__ Wv, const float* __restrict__ bk,
                   const float* __restrict__ bv, short* __restrict__ Kb,
                   short* __restrict__ Vt) {
  __shared__ short Vlds[256 * 72];  // V transpose staging
  const int m0 = blockIdx.x * 64;
  const int tid = threadIdx.x;
  const int w = tid >> 6, lane = tid & 63, quad = lane >> 4, c = lane & 15;

  f4 accK[4][4], accV[4][4];
  const f4 z = {0.f, 0.f, 0.f, 0.f};
#pragma unroll
  for (int i = 0; i < 4; i++)
#pragma unroll
    for (int j = 0; j < 4; j++) { accK[i][j] = z; accV[i][j] = z; }

#pragma unroll
  for (int ks = 0; ks < 8; ks++) {
    bf8 a[4], bK[4], bV[4];
#pragma unroll
    for (int ms = 0; ms < 4; ms++)  // A[m=lane&15][k=quad*8+j]
      a[ms] = cvtp(x + (m0 + ms * 16 + c) * 256 + ks * 32 + quad * 8);
#pragma unroll
    for (int e = 0; e < 4; e++) {   // B[k=d][n=e] = W[e][d] (row-major W)
      const int off = ((w * 4 + e) * 16 + c) * 256 + ks * 32 + quad * 8;
      bK[e] = cvtp(Wk + off);
      bV[e] = cvtp(Wv + off);
    }
#pragma unroll
    for (int ms = 0; ms < 4; ms++)
#pragma unroll
      for (int e = 0; e < 4; e++) {
        accK[ms][e] = mfma16(a[ms], bK[e], accK[ms][e]);
        accV[ms][e] = mfma16(a[ms], bV[e], accV[ms][e]);
      }
  }

  float bbk[4], bbv[4];
#pragma unroll
  for (int e = 0; e < 4; e++) {
    bbk[e] = bk[(w * 4 + e) * 16 + c];
    bbv[e] = bv[(w * 4 + e) * 16 + c];
  }
  // K: row-major.  C/D: col=lane&15, row=quad*4+reg
#pragma unroll
  for (int ms = 0; ms < 4; ms++)
#pragma unroll
    for (int e = 0; e < 4; e++)
#pragma unroll
      for (int r = 0; r < 4; r++)
        Kb[(m0 + ms * 16 + quad * 4 + r) * 256 + (w * 4 + e) * 16 + c] =
            f2bf(accK[ms][e][r] + bbk[e]);
  // V: transpose through LDS, emit tiled [tt][256 d][64 n]
#pragma unroll
  for (int ms = 0; ms < 4; ms++)
#pragma unroll
    for (int e = 0; e < 4; e++)
#pragma unroll
      for (int r = 0; r < 4; r++)
        Vlds[((w * 4 + e) * 16 + c) * 72 + ms * 16 + quad * 4 + r] =
            f2bf(accV[ms][e][r] + bbv[e]);
  __syncthreads();
  const int tt = m0 >> 6;
#pragma unroll
  for (int k2 = 0; k2 < 8; k2++) {
    int eidx = k2 * 2048 + tid * 8;
    *(bf8*)(Vt + tt * 16384 + eidx) =
        *(const bf8*)&Vlds[(eidx >> 6) * 72 + (eidx & 63)];
  }
}

// ---------------- kernel C: flash attention (Q fused) ----------------
// 512 WGs (2/CU). batch = bx&3 (one batch per XCD under %8 round-robin).
// Q built in-kernel: 32 rows = x(32x256).Wq^T + bq, scaled by log2e/16,
// LDS transpose C-layout -> A-frags. Mask via bitmask words (L2-resident).
// Fixed-max softmax P = exp2(S_masked); P dbuf + lgkm-only barrier.
__launch_bounds__(256, 2)
__global__ void flash(const float* __restrict__ x, const float* __restrict__ Wq,
                      const float* __restrict__ bq, const short* __restrict__ Kb,
                      const short* __restrict__ Vt, const u64* __restrict__ bm,
                      float* __restrict__ out) {
  __shared__ short Plds[2][32 * 76];  // P dbuf, stride 76 (conflict-free)
  __shared__ short Qst[32 * 264];     // Q staging, stride 264 (2-way max)
  const int bx = blockIdx.x;
  const int batch = bx & 3;
  const int q0g = batch * 4096 + (bx >> 2) * 32;  // global flat row base
  const int tid = threadIdx.x;
  const int w = tid >> 6, lane = tid & 63, quad = lane >> 4, c = lane & 15;
  const f4 z = {0.f, 0.f, 0.f, 0.f};

  // ---- build Q (folds softmax scale + base-2: log2(e)/16) ----
  {
    f4 qacc[2][4];
#pragma unroll
    for (int i = 0; i < 2; i++)
#pragma unroll
      for (int j = 0; j < 4; j++) qacc[i][j] = z;
#pragma unroll
    for (int ks = 0; ks < 8; ks++) {
      bf8 a[2], b[4];
#pragma unroll
      for (int ms = 0; ms < 2; ms++)
        a[ms] = cvtp(x + (q0g + ms * 16 + c) * 256 + ks * 32 + quad * 8);
#pragma unroll
      for (int e = 0; e < 4; e++)
        b[e] = cvtp(Wq + ((w * 4 + e) * 16 + c) * 256 + ks * 32 + quad * 8);
#pragma unroll
      for (int ms = 0; ms < 2; ms++)
#pragma unroll
        for (int e = 0; e < 4; e++) qacc[ms][e] = mfma16(a[ms], b[e], qacc[ms][e]);
    }
    const float sc = 0.09016844005556021f;  // log2(e)/sqrt(D)
#pragma unroll
    for (int e = 0; e < 4; e++) {
      const float bb = bq[(w * 4 + e) * 16 + c];
#pragma unroll
      for (int ms = 0; ms < 2; ms++)
#pragma unroll
        for (int r = 0; r < 4; r++)
          Qst[(ms * 16 + quad * 4 + r) * 264 + (w * 4 + e) * 16 + c] =
              f2bf((qacc[ms][e][r] + bb) * sc);
    }
  }
  __syncthreads();
  bf8 aq[2][8];  // A-frags: 64 VGPR, resident
#pragma unroll
  for (int ms = 0; ms < 2; ms++)
#pragma unroll
    for (int ks = 0; ks < 8; ks++)
      aq[ms][ks] = *(const bf8*)&Qst[(ms * 16 + c) * 264 + ks * 32 + quad * 8];

  f4 accO[2][4], lacc[2];
#pragma unroll
  for (int ms = 0; ms < 2; ms++) {
    lacc[ms] = z;
#pragma unroll
    for (int ds = 0; ds < 4; ds++) accO[ms][ds] = z;
  }
  const short* kb = Kb + batch * 4096 * 256;
  const short* vb = Vt + batch * 1048576;
  const u64* bmb = bm + (size_t)q0g * 64;  // word[row*64 + t]
  const bf8 ONES = {0x3F80, 0x3F80, 0x3F80, 0x3F80, 0x3F80, 0x3F80, 0x3F80, 0x3F80};
  const int lane16 = w * 16 + c;  // this lane's col bit within a tile

  u64 mcw[8], mnw[8];  // bitmask words, depth-1 prefetch (L2-latency class)
#pragma unroll
  for (int ms = 0; ms < 2; ms++)
#pragma unroll
    for (int r = 0; r < 4; r++)
      mcw[ms * 4 + r] = bmb[(ms * 16 + quad * 4 + r) * 64];

  for (int t = 0; t < 64; t++) {
    const int n0 = t * 64;
    const int tn = (t < 63) ? t + 1 : 63;
#pragma unroll
    for (int ms = 0; ms < 2; ms++)
#pragma unroll
      for (int r = 0; r < 4; r++)
        mnw[ms * 4 + r] = bmb[(ms * 16 + quad * 4 + r) * 64 + tn];

    // ---- K frags (JIT from L2) + S = Q' K^T ----
    bf8 bk_[8];
#pragma unroll
    for (int ks = 0; ks < 8; ks++)  // B[k][n]=K[n][k]: 16B contiguous
      bk_[ks] = *(const bf8*)(kb + (n0 + w * 16 + c) * 256 + ks * 32 + quad * 8);
    bf8 bv_[2][4];
#pragma unroll
    for (int k2 = 0; k2 < 2; k2++)
#pragma unroll
      for (int ds = 0; ds < 4; ds++)
        bv_[k2][ds] = *(const bf8*)(vb + t * 16384 + (w * 64 + ds * 16 + c) * 64 +
                                    k2 * 32 + quad * 8);
    f4 s[2];
#pragma unroll
    for (int ms = 0; ms < 2; ms++) s[ms] = z;
#pragma unroll
    for (int ks = 0; ks < 8; ks++)
#pragma unroll
      for (int ms = 0; ms < 2; ms++) s[ms] = mfma16(aq[ms][ks], bk_[ks], s[ms]);

    // ---- P = exp2(masked S) -> LDS (C-layout -> A-layout) ----
    short* pw = &Plds[t & 1][0];
#pragma unroll
    for (int ms = 0; ms < 2; ms++)
#pragma unroll
      for (int r = 0; r < 4; r++) {
        const int on = (int)((mcw[ms * 4 + r] >> lane16) & 1ull);
        float sv = on ? s[ms][r] : -INFINITY;
        pw[(ms * 16 + quad * 4 + r) * 76 + w * 16 + c] =
            f2bf(__builtin_amdgcn_exp2f(sv));
      }
    lds_barrier();  // LDS-visibility only

    // ---- O += P V ; row-sum via ones-frag MFMA ----
#pragma unroll
    for (int k2 = 0; k2 < 2; k2++) {
      bf8 ap[2];
#pragma unroll
      for (int ms = 0; ms < 2; ms++)  // A[m=lane&15][k=quad*8+j]
        ap[ms] = *(const bf8*)&pw[(ms * 16 + c) * 76 + k2 * 32 + quad * 8];
#pragma unroll
      for (int ms = 0; ms < 2; ms++) {
        lacc[ms] = mfma16(ap[ms], ONES, lacc[ms]);
#pragma unroll
        for (int ds = 0; ds < 4; ds++)
          accO[ms][ds] = mfma16(ap[ms], bv_[k2][ds], accO[ms][ds]);
      }
    }
#pragma unroll
    for (int i2 = 0; i2 < 8; i2++) mcw[i2] = mnw[i2];
  }

  // ---- epilogue: O / l ----
  float* ob = out + (size_t)q0g * 256;
#pragma unroll
  for (int ms = 0; ms < 2; ms++) {
    f4 rl;
#pragma unroll
    for (int r = 0; r < 4; r++) rl[r] = __builtin_amdgcn_rcpf(lacc[ms][r]);
#pragma unroll
    for (int ds = 0; ds < 4; ds++)
#pragma unroll
      for (int r = 0; r < 4; r++)
        ob[(ms * 16 + quad * 4 + r) * 256 + w * 64 + ds * 16 + c] =
            accO[ms][ds][r] * rl[r];
  }
}

extern "C" void kernel_launch(void* const* d_in, const int* in_sizes, int n_in,
                              void* d_out, int out_size, void* d_ws, size_t ws_size,
                              hipStream_t stream) {
  const float* x = (const float*)d_in[0];
  const int* mask = (const int*)d_in[1];
  const float* Wq = (const float*)d_in[2];
  const float* bq = (const float*)d_in[3];
  const float* Wk = (const float*)d_in[4];
  const float* bk = (const float*)d_in[5];
  const float* Wv = (const float*)d_in[6];
  const float* bv = (const float*)d_in[7];
  float* out = (float*)d_out;

  char* ws = (char*)d_ws;  // 24 MiB total
  short* Kb = (short*)ws;
  short* Vt = (short*)(ws + (8u << 20));
  u64* bm = (u64*)(ws + (16u << 20));

  maskc<<<512, 256, 0, stream>>>(mask, bm);
  kv<<<256, 256, 0, stream>>>(x, Wk, Wv, bk, bv, Kb, Vt);
  flash<<<512, 256, 0, stream>>>(x, Wq, bq, Kb, Vt, bm, out);
}

// Round 6
// 657.546 us; speedup vs baseline: 1.0554x; 1.0554x over previous
//
#include <hip/hip_runtime.h>

// Self-attention, B=4, N=4096, D=256 (single head over full D).
//   Q = x Wq^T + bq ; K,V likewise ; S = Q K^T ; mask==0 -> -inf ;
//   attn = softmax(S/16) ; out = attn V        (fp32 in/out)
// R6: R2-R5 all ~275-296us regardless of traffic/occupancy -> the compiler
//     sinks every load to its use (VGPR 112-128 proves prefetch was deleted)
//     and each tile serializes on exposed L2/LLC latency. Fix: ALL loop
//     global loads are inline-asm (unsinkable), software-pipelined one tile
//     ahead, with explicit s_waitcnt vmcnt(N) asms that thread the loaded
//     values as operands (dependency-ordered). No compiler vm-ops in the
//     loop. Raw mask returns (streams at HBM BW under the pipeline);
//     maskc/bitmask deleted; Q back in the projection kernel.
// ws: Qs bf16 8MiB | Kb bf16 8MiB | Vt bf16 8MiB  (= 24MiB, proven)

#define DEV static __device__ __forceinline__

typedef __attribute__((ext_vector_type(8))) short bf8;   // 8 bf16 (4 VGPR)
typedef __attribute__((ext_vector_type(4))) float f4;

DEV short f2bf(float x) {  // fp32 -> bf16 RNE (inputs finite)
  unsigned u = __builtin_bit_cast(unsigned, x);
  u += 0x7FFFu + ((u >> 16) & 1u);
  return (short)(u >> 16);
}

DEV bf8 cvt8(f4 a, f4 b) {
  bf8 r;
  r[0] = f2bf(a[0]); r[1] = f2bf(a[1]); r[2] = f2bf(a[2]); r[3] = f2bf(a[3]);
  r[4] = f2bf(b[0]); r[5] = f2bf(b[1]); r[6] = f2bf(b[2]); r[7] = f2bf(b[3]);
  return r;
}

DEV bf8 cvtp(const float* p) { return cvt8(*(const f4*)p, *(const f4*)(p + 4)); }

DEV f4 mfma16(bf8 a, bf8 b, f4 c) {
  return __builtin_amdgcn_mfma_f32_16x16x32_bf16(a, b, c, 0, 0, 0);
}

// LDS-only barrier (P dbuf visibility); global loads stay in flight.
DEV void lds_barrier() {
  __asm__ __volatile__("s_waitcnt lgkmcnt(0)\ns_barrier" ::: "memory");
}

DEV void ld16(bf8& d, const short* p) {  // unsinkable 16B global load
  __asm__ __volatile__("global_load_dwordx4 %0, %1, off" : "=v"(d) : "v"(p));
}
DEV void ld4(int& d, const int* p) {     // unsinkable 4B global load
  __asm__ __volatile__("global_load_dword %0, %1, off" : "=v"(d) : "v"(p));
}

// ---------------- kernel 1: Q,K,V projection ----------------
// grid (256, 3): x=row-block of 64, y=which (0=Q,1=K,2=V). 4 waves.
// Weights read fp32 + inline cvt. Q pre-scaled by log2(e)/16 (folds the
// softmax 1/sqrt(D) and base-2 exp). V emitted transposed+tiled
// [tile][256 d][64 n] so flash PV B-frags are contiguous 16B.
__launch_bounds__(256, 2)
__global__ void qkv(const float* __restrict__ x, const float* __restrict__ Wq,
                    const float* __restrict__ Wk, const float* __restrict__ Wv,
                    const float* __restrict__ bq, const float* __restrict__ bk,
                    const float* __restrict__ bv, short* __restrict__ Qs,
                    short* __restrict__ Kb, short* __restrict__ Vt) {
  __shared__ short Vlds[256 * 72];  // V transpose staging
  const int which = blockIdx.y;
  const int m0 = blockIdx.x * 64;
  const int tid = threadIdx.x;
  const int w = tid >> 6, lane = tid & 63, quad = lane >> 4, c = lane & 15;
  const float* W = (which == 0) ? Wq : (which == 1) ? Wk : Wv;
  const float* bias = (which == 0) ? bq : (which == 1) ? bk : bv;

  f4 acc[4][4];
  const f4 z = {0.f, 0.f, 0.f, 0.f};
#pragma unroll
  for (int i = 0; i < 4; i++)
#pragma unroll
    for (int j = 0; j < 4; j++) acc[i][j] = z;

#pragma unroll
  for (int ks = 0; ks < 8; ks++) {
    bf8 a[4], b[4];
#pragma unroll
    for (int ms = 0; ms < 4; ms++)  // A[m=lane&15][k=quad*8+j]
      a[ms] = cvtp(x + (m0 + ms * 16 + c) * 256 + ks * 32 + quad * 8);
#pragma unroll
    for (int e = 0; e < 4; e++)     // B[k=d][n=e] = W[e][d] (row-major W)
      b[e] = cvtp(W + ((w * 4 + e) * 16 + c) * 256 + ks * 32 + quad * 8);
#pragma unroll
    for (int ms = 0; ms < 4; ms++)
#pragma unroll
      for (int e = 0; e < 4; e++) acc[ms][e] = mfma16(a[ms], b[e], acc[ms][e]);
  }

  float bb[4];
#pragma unroll
  for (int e = 0; e < 4; e++) bb[e] = bias[(w * 4 + e) * 16 + c];
  const float sc = (which == 0) ? 0.09016844005556021f : 1.0f;  // log2e/16

  if (which < 2) {
    short* dst = (which == 0) ? Qs : Kb;
#pragma unroll
    for (int ms = 0; ms < 4; ms++)
#pragma unroll
      for (int e = 0; e < 4; e++)
#pragma unroll
        for (int r = 0; r < 4; r++)  // C/D: col=lane&15, row=quad*4+reg
          dst[(m0 + ms * 16 + quad * 4 + r) * 256 + (w * 4 + e) * 16 + c] =
              f2bf((acc[ms][e][r] + bb[e]) * sc);
  } else {
    // V: transpose through LDS, emit tiled [tt][256 d][64 n]
#pragma unroll
    for (int ms = 0; ms < 4; ms++)
#pragma unroll
      for (int e = 0; e < 4; e++)
#pragma unroll
        for (int r = 0; r < 4; r++)
          Vlds[((w * 4 + e) * 16 + c) * 72 + ms * 16 + quad * 4 + r] =
              f2bf(acc[ms][e][r] + bb[e]);
    __syncthreads();
    const int tt = m0 >> 6;
#pragma unroll
    for (int k2 = 0; k2 < 8; k2++) {
      int eidx = k2 * 2048 + tid * 8;
      *(bf8*)(Vt + tt * 16384 + eidx) =
          *(const bf8*)&Vlds[(eidx >> 6) * 72 + (eidx & 63)];
    }
  }
}

// ---------------- kernel 2: flash attention ----------------
// 512 WGs (2/CU). batch = bx&3 (per-XCD batch affinity under %8 dispatch).
// Wave w: n-strip [n0+w*16) of S ; d-strip [w*64) of PV. Fixed-max softmax
// P = exp2(S_masked) (|S'| << 127). Pipeline: per tile issue V(t) [oldest],
// then K(t+1)+mask(t+1); QK/P/barrier covers V latency -> vmcnt(16) frees
// V; vmcnt(0) at tile end lands ~1300cyc after K(t+1)/mask(t+1) issue.
__launch_bounds__(256, 2)
__global__ void flash(const short* __restrict__ Qs, const short* __restrict__ Kb,
                      const short* __restrict__ Vt, const int* __restrict__ mask,
                      float* __restrict__ out) {
  __shared__ short Plds[2][32 * 76];  // P dbuf, stride 76 (conflict-free)
  const int bx = blockIdx.x;
  const int batch = bx & 3;
  const int q0 = (bx >> 2) * 32;
  const int tid = threadIdx.x;
  const int w = tid >> 6, lane = tid & 63, quad = lane >> 4, c = lane & 15;

  const short* kb = Kb + batch * 4096 * 256;
  const short* vb = Vt + batch * 1048576;
  const int* mb = mask + batch * 16777216;

  // ---- issue tile-0 prefetch first (K frags + mask), via asm ----
  bf8 kc[8], kn[8];
  int mc[8], mn[8];
#pragma unroll
  for (int ks = 0; ks < 8; ks++)
    ld16(kc[ks], kb + (w * 16 + c) * 256 + ks * 32 + quad * 8);
#pragma unroll
  for (int ms = 0; ms < 2; ms++)
#pragma unroll
    for (int r = 0; r < 4; r++)
      ld4(mc[ms * 4 + r], mb + (q0 + ms * 16 + quad * 4 + r) * 4096 + w * 16 + c);

  // ---- Q fragments (compiler loads; prologue-only waitcnt interference) ----
  bf8 aq[2][8];
  const short* qb = Qs + (batch * 4096 + q0) * 256;
#pragma unroll
  for (int ms = 0; ms < 2; ms++)
#pragma unroll
    for (int ks = 0; ks < 8; ks++)
      aq[ms][ks] = *(const bf8*)(qb + (ms * 16 + c) * 256 + ks * 32 + quad * 8);

  const f4 z = {0.f, 0.f, 0.f, 0.f};
  f4 accO[2][4], lacc[2];
#pragma unroll
  for (int ms = 0; ms < 2; ms++) {
    lacc[ms] = z;
#pragma unroll
    for (int ds = 0; ds < 4; ds++) accO[ms][ds] = z;
  }
  const bf8 ONES = {0x3F80, 0x3F80, 0x3F80, 0x3F80, 0x3F80, 0x3F80, 0x3F80, 0x3F80};

  // drain tile-0 prefetch (threads values -> ordered before first use)
  __asm__ __volatile__("s_waitcnt vmcnt(0)"
      : "+v"(kc[0]), "+v"(kc[1]), "+v"(kc[2]), "+v"(kc[3]),
        "+v"(kc[4]), "+v"(kc[5]), "+v"(kc[6]), "+v"(kc[7]),
        "+v"(mc[0]), "+v"(mc[1]), "+v"(mc[2]), "+v"(mc[3]),
        "+v"(mc[4]), "+v"(mc[5]), "+v"(mc[6]), "+v"(mc[7]));

#pragma unroll 2
  for (int t = 0; t < 64; t++) {
    const int tn = (t < 63) ? t + 1 : 63;
    // ---- issue V(t) first (oldest), then K(t+1), mask(t+1) ----
    bf8 vc[2][4];
#pragma unroll
    for (int k2 = 0; k2 < 2; k2++)
#pragma unroll
      for (int ds = 0; ds < 4; ds++)
        ld16(vc[k2][ds], vb + t * 16384 + (w * 64 + ds * 16 + c) * 64 +
                         k2 * 32 + quad * 8);
#pragma unroll
    for (int ks = 0; ks < 8; ks++)
      ld16(kn[ks], kb + (tn * 64 + w * 16 + c) * 256 + ks * 32 + quad * 8);
#pragma unroll
    for (int ms = 0; ms < 2; ms++)
#pragma unroll
      for (int r = 0; r < 4; r++)
        ld4(mn[ms * 4 + r],
            mb + (q0 + ms * 16 + quad * 4 + r) * 4096 + tn * 64 + w * 16 + c);

    // ---- S = Q' K^T on kc (arrived last tile) ----
    f4 s[2];
#pragma unroll
    for (int ms = 0; ms < 2; ms++) s[ms] = z;
#pragma unroll
    for (int ks = 0; ks < 8; ks++)
#pragma unroll
      for (int ms = 0; ms < 2; ms++) s[ms] = mfma16(aq[ms][ks], kc[ks], s[ms]);

    // ---- P = exp2(masked S) -> LDS (C-layout -> A-layout) ----
    short* pw = &Plds[t & 1][0];
#pragma unroll
    for (int ms = 0; ms < 2; ms++)
#pragma unroll
      for (int r = 0; r < 4; r++) {
        float sv = (mc[ms * 4 + r] != 0) ? s[ms][r] : -INFINITY;
        pw[(ms * 16 + quad * 4 + r) * 76 + w * 16 + c] =
            f2bf(__builtin_amdgcn_exp2f(sv));
      }
    lds_barrier();  // LDS-visibility only

    // ---- release V(t): 24 outstanding -> wait to 16 drains oldest 8 ----
    __asm__ __volatile__("s_waitcnt vmcnt(16)"
        : "+v"(vc[0][0]), "+v"(vc[0][1]), "+v"(vc[0][2]), "+v"(vc[0][3]),
          "+v"(vc[1][0]), "+v"(vc[1][1]), "+v"(vc[1][2]), "+v"(vc[1][3]));

    // ---- O += P V ; row-sum via ones-frag MFMA ----
#pragma unroll
    for (int k2 = 0; k2 < 2; k2++) {
      bf8 ap[2];
#pragma unroll
      for (int ms = 0; ms < 2; ms++)  // A[m=lane&15][k=quad*8+j]
        ap[ms] = *(const bf8*)&pw[(ms * 16 + c) * 76 + k2 * 32 + quad * 8];
#pragma unroll
      for (int ms = 0; ms < 2; ms++) {
        lacc[ms] = mfma16(ap[ms], ONES, lacc[ms]);
#pragma unroll
        for (int ds = 0; ds < 4; ds++)
          accO[ms][ds] = mfma16(ap[ms], vc[k2][ds], accO[ms][ds]);
      }
    }

    // ---- end of tile: K(t+1)/mask(t+1) resident for next iter ----
    __asm__ __volatile__("s_waitcnt vmcnt(0)"
        : "+v"(kn[0]), "+v"(kn[1]), "+v"(kn[2]), "+v"(kn[3]),
          "+v"(kn[4]), "+v"(kn[5]), "+v"(kn[6]), "+v"(kn[7]),
          "+v"(mn[0]), "+v"(mn[1]), "+v"(mn[2]), "+v"(mn[3]),
          "+v"(mn[4]), "+v"(mn[5]), "+v"(mn[6]), "+v"(mn[7]));
#pragma unroll
    for (int ks = 0; ks < 8; ks++) kc[ks] = kn[ks];
#pragma unroll
    for (int i2 = 0; i2 < 8; i2++) mc[i2] = mn[i2];
  }

  // ---- epilogue: O / l ----
  float* ob = out + (batch * 4096 + q0) * 256;
#pragma unroll
  for (int ms = 0; ms < 2; ms++) {
    f4 rl;
#pragma unroll
    for (int r = 0; r < 4; r++) rl[r] = __builtin_amdgcn_rcpf(lacc[ms][r]);
#pragma unroll
    for (int ds = 0; ds < 4; ds++)
#pragma unroll
      for (int r = 0; r < 4; r++)
        ob[(ms * 16 + quad * 4 + r) * 256 + w * 64 + ds * 16 + c] =
            accO[ms][ds][r] * rl[r];
  }
}

extern "C" void kernel_launch(void* const* d_in, const int* in_sizes, int n_in,
                              void* d_out, int out_size, void* d_ws, size_t ws_size,
                              hipStream_t stream) {
  const float* x = (const float*)d_in[0];
  const int* mask = (const int*)d_in[1];
  const float* Wq = (const float*)d_in[2];
  const float* bq = (const float*)d_in[3];
  const float* Wk = (const float*)d_in[4];
  const float* bk = (const float*)d_in[5];
  const float* Wv = (const float*)d_in[6];
  const float* bv = (const float*)d_in[7];
  float* out = (float*)d_out;

  char* ws = (char*)d_ws;  // 24 MiB
  short* Qs = (short*)ws;
  short* Kb = (short*)(ws + (8u << 20));
  short* Vt = (short*)(ws + (16u << 20));

  qkv<<<dim3(256, 3), 256, 0, stream>>>(x, Wq, Wk, Wv, bq, bk, bv, Qs, Kb, Vt);
  flash<<<512, 256, 0, stream>>>(Qs, Kb, Vt, mask, out);
}

// Round 7
// 564.012 us; speedup vs baseline: 1.2305x; 1.1658x over previous
//
#include <hip/hip_runtime.h>

// Self-attention, B=4, N=4096, D=256 (single head over full D).
//   Q = x Wq^T + bq ; K,V likewise ; S = Q K^T ; mask==0 -> -inf ;
//   attn = softmax(S/16) ; out = attn V        (fp32 in/out)
// R7: R2-R6 all ~275-343us, tile period ~11k cyc, nothing saturated ->
//     concurrency-starved: per-lane register loads cap in-flight bytes and
//     fragment loads are 16-line divergent. m97-style fix:
//     - K tile staged to LDS via global_load_lds w=16 (coalesced 16B/lane),
//       XOR-swizzled chunks so frag ds_read_b128 is <=2-way (free).
//     - mask staged to LDS ring DEPTH 4 (deep async vmcnt queue; ~16MB
//       device-wide in flight -> mask streams at HBM pace).
//     - V in asm regs (issued early, used 2 barriers later).
//     - hand waitcnts: vmcnt(2)+barrier at tile end (K ready), lgkm-only
//       mid barrier, vmcnt(10) before PV (V ready, K/mask stay in flight).
// ws: Qs bf16 8MiB | Kb bf16 8MiB | Vt bf16 8MiB  (= 24MiB, proven)

#define DEV static __device__ __forceinline__

typedef __attribute__((ext_vector_type(8))) short bf8;   // 8 bf16 (4 VGPR)
typedef __attribute__((ext_vector_type(4))) float f4;
typedef const __attribute__((address_space(1))) unsigned int* gp1;
typedef __attribute__((address_space(3))) unsigned int* lp3;

DEV short f2bf(float x) {  // fp32 -> bf16 RNE (inputs finite)
  unsigned u = __builtin_bit_cast(unsigned, x);
  u += 0x7FFFu + ((u >> 16) & 1u);
  return (short)(u >> 16);
}

DEV bf8 cvt8(f4 a, f4 b) {
  bf8 r;
  r[0] = f2bf(a[0]); r[1] = f2bf(a[1]); r[2] = f2bf(a[2]); r[3] = f2bf(a[3]);
  r[4] = f2bf(b[0]); r[5] = f2bf(b[1]); r[6] = f2bf(b[2]); r[7] = f2bf(b[3]);
  return r;
}

DEV bf8 cvtp(const float* p) { return cvt8(*(const f4*)p, *(const f4*)(p + 4)); }

DEV f4 mfma16(bf8 a, bf8 b, f4 c) {
  return __builtin_amdgcn_mfma_f32_16x16x32_bf16(a, b, c, 0, 0, 0);
}

DEV void gl_lds16(const void* g, void* l) {  // async global->LDS, 16B/lane
  __builtin_amdgcn_global_load_lds((gp1)g, (lp3)l, 16, 0, 0);
}

DEV void ld16(bf8& d, const short* p) {  // unsinkable 16B global load
  __asm__ __volatile__("global_load_dwordx4 %0, %1, off" : "=v"(d) : "v"(p));
}

// ---------------- kernel 1: Q,K,V projection (unchanged from R6) ----------
__launch_bounds__(256, 2)
__global__ void qkv(const float* __restrict__ x, const float* __restrict__ Wq,
                    const float* __restrict__ Wk, const float* __restrict__ Wv,
                    const float* __restrict__ bq, const float* __restrict__ bk,
                    const float* __restrict__ bv, short* __restrict__ Qs,
                    short* __restrict__ Kb, short* __restrict__ Vt) {
  __shared__ short Vlds[256 * 72];  // V transpose staging
  const int which = blockIdx.y;
  const int m0 = blockIdx.x * 64;
  const int tid = threadIdx.x;
  const int w = tid >> 6, lane = tid & 63, quad = lane >> 4, c = lane & 15;
  const float* W = (which == 0) ? Wq : (which == 1) ? Wk : Wv;
  const float* bias = (which == 0) ? bq : (which == 1) ? bk : bv;

  f4 acc[4][4];
  const f4 z = {0.f, 0.f, 0.f, 0.f};
#pragma unroll
  for (int i = 0; i < 4; i++)
#pragma unroll
    for (int j = 0; j < 4; j++) acc[i][j] = z;

#pragma unroll
  for (int ks = 0; ks < 8; ks++) {
    bf8 a[4], b[4];
#pragma unroll
    for (int ms = 0; ms < 4; ms++)  // A[m=lane&15][k=quad*8+j]
      a[ms] = cvtp(x + (m0 + ms * 16 + c) * 256 + ks * 32 + quad * 8);
#pragma unroll
    for (int e = 0; e < 4; e++)     // B[k=d][n=e] = W[e][d] (row-major W)
      b[e] = cvtp(W + ((w * 4 + e) * 16 + c) * 256 + ks * 32 + quad * 8);
#pragma unroll
    for (int ms = 0; ms < 4; ms++)
#pragma unroll
      for (int e = 0; e < 4; e++) acc[ms][e] = mfma16(a[ms], b[e], acc[ms][e]);
  }

  float bb[4];
#pragma unroll
  for (int e = 0; e < 4; e++) bb[e] = bias[(w * 4 + e) * 16 + c];
  const float sc = (which == 0) ? 0.09016844005556021f : 1.0f;  // log2e/16

  if (which < 2) {
    short* dst = (which == 0) ? Qs : Kb;
#pragma unroll
    for (int ms = 0; ms < 4; ms++)
#pragma unroll
      for (int e = 0; e < 4; e++)
#pragma unroll
        for (int r = 0; r < 4; r++)  // C/D: col=lane&15, row=quad*4+reg
          dst[(m0 + ms * 16 + quad * 4 + r) * 256 + (w * 4 + e) * 16 + c] =
              f2bf((acc[ms][e][r] + bb[e]) * sc);
  } else {
#pragma unroll
    for (int ms = 0; ms < 4; ms++)
#pragma unroll
      for (int e = 0; e < 4; e++)
#pragma unroll
        for (int r = 0; r < 4; r++)
          Vlds[((w * 4 + e) * 16 + c) * 72 + ms * 16 + quad * 4 + r] =
              f2bf(acc[ms][e][r] + bb[e]);
    __syncthreads();
    const int tt = m0 >> 6;
#pragma unroll
    for (int k2 = 0; k2 < 8; k2++) {
      int eidx = k2 * 2048 + tid * 8;
      *(bf8*)(Vt + tt * 16384 + eidx) =
          *(const bf8*)&Vlds[(eidx >> 6) * 72 + (eidx & 63)];
    }
  }
}

// ---------------- kernel 2: flash attention ----------------
// 512 WGs (2/CU). batch = bx&3 (per-XCD batch affinity). Per tile:
//  [K(t),m(t) in LDS]  issue V(t) regs -> QK(frag ds_reads, swizzled)
//  -> P=exp2(masked S) -> B2(lgkm+barrier) -> stage K(t+1), m(t+4)
//  -> vmcnt(10) [V ready] -> PV -> B1(vmcnt(2)+barrier) [K(t+1) ready].
__launch_bounds__(256, 2)
__global__ void flash(const short* __restrict__ Qs, const short* __restrict__ Kb,
                      const short* __restrict__ Vt, const int* __restrict__ mask,
                      float* __restrict__ out) {
  __shared__ short Klds[16384];    // K tile 64x256, chunk-XOR-swizzled, 32KB
  __shared__ int Mlds[4][2048];    // mask ring: 4 tiles x 32row x 64col, 32KB
  __shared__ short Plds[2][32 * 76];  // P dbuf, stride 76 (conflict-free)
  const int bx = blockIdx.x;
  const int batch = bx & 3;
  const int q0 = (bx >> 2) * 32;
  const int tid = threadIdx.x;
  const int w = tid >> 6, lane = tid & 63, quad = lane >> 4, c = lane & 15;

  const short* kb = Kb + batch * 4096 * 256;
  const short* vb = Vt + batch * 1048576;
  const int* mb = mask + batch * 16777216;

  // per-thread staging geometry
  const int krow = tid >> 5;            // row-in-8-row-line (0..7)
  const int kch = tid & 31;             // LDS chunk this thread fills
  // mask staging: 16 rows per 4KB line
  const int mrow = tid >> 4, mco = (tid & 15) * 4;

  // ---- prologue: stage K(0) then mask(0..3) ----
#pragma unroll
  for (int l = 0; l < 8; l++) {
    const int row = l * 8 + krow;
    const int chg = (kch & 16) | ((kch ^ row) & 15);  // involutive swizzle
    gl_lds16(kb + row * 256 + chg * 8, &Klds[l * 2048 + tid * 8]);
  }
#pragma unroll
  for (int tt = 0; tt < 4; tt++)
#pragma unroll
    for (int l2 = 0; l2 < 2; l2++)
      gl_lds16(mb + (q0 + l2 * 16 + mrow) * 4096 + tt * 64 + mco,
               &Mlds[tt][l2 * 1024 + tid * 4]);

  // ---- Q fragments (compiler loads; prologue-only) ----
  bf8 aq[2][8];
  const short* qb = Qs + (batch * 4096 + q0) * 256;
#pragma unroll
  for (int ms = 0; ms < 2; ms++)
#pragma unroll
    for (int ks = 0; ks < 8; ks++)
      aq[ms][ks] = *(const bf8*)(qb + (ms * 16 + c) * 256 + ks * 32 + quad * 8);

  const f4 z = {0.f, 0.f, 0.f, 0.f};
  f4 accO[2][4], lacc[2];
#pragma unroll
  for (int ms = 0; ms < 2; ms++) {
    lacc[ms] = z;
#pragma unroll
    for (int ds = 0; ds < 4; ds++) accO[ms][ds] = z;
  }
  const bf8 ONES = {0x3F80, 0x3F80, 0x3F80, 0x3F80, 0x3F80, 0x3F80, 0x3F80, 0x3F80};

  // K(0)+mask(0) arrived; masks(1..3) may still fly (3x2 issues = 6)
  __asm__ __volatile__("s_waitcnt vmcnt(6)\ns_barrier" ::: "memory");

  for (int t = 0; t < 64; t++) {
    // ---- issue V(t) into regs (consumed after B2, ~2 barriers later) ----
    bf8 vc[2][4];
#pragma unroll
    for (int k2 = 0; k2 < 2; k2++)
#pragma unroll
      for (int ds = 0; ds < 4; ds++)
        ld16(vc[k2][ds], vb + t * 16384 + (w * 64 + ds * 16 + c) * 64 +
                         k2 * 32 + quad * 8);

    // ---- S = Q' K^T from swizzled LDS (wave strip: rows w*16+c) ----
    f4 s[2];
#pragma unroll
    for (int ms = 0; ms < 2; ms++) s[ms] = z;
#pragma unroll
    for (int ks = 0; ks < 8; ks++) {
      const int ch = ks * 4 + quad;
      const int sw = (ch & 16) | ((ch ^ c) & 15);
      const bf8 kf = *(const bf8*)&Klds[(w * 16 + c) * 256 + sw * 8];
#pragma unroll
      for (int ms = 0; ms < 2; ms++) s[ms] = mfma16(aq[ms][ks], kf, s[ms]);
    }

    // ---- P = exp2(masked S) -> LDS (C-layout -> A-layout) ----
    const int* mrow_p = &Mlds[t & 3][w * 16 + c];
    short* pw = &Plds[t & 1][0];
#pragma unroll
    for (int ms = 0; ms < 2; ms++)
#pragma unroll
      for (int r = 0; r < 4; r++) {
        const int mv = mrow_p[(ms * 16 + quad * 4 + r) * 64];
        float sv = (mv != 0) ? s[ms][r] : -INFINITY;
        pw[(ms * 16 + quad * 4 + r) * 76 + w * 16 + c] =
            f2bf(__builtin_amdgcn_exp2f(sv));
      }
    // B2: P (and this tile's LDS reads) visible; VM queue untouched
    __asm__ __volatile__("s_waitcnt lgkmcnt(0)\ns_barrier" ::: "memory");

    // ---- stage K(t+1) + mask(t+4) (async, consumed next iters) ----
    const int tk = (t < 63) ? t + 1 : 63;
    const short* kbt = kb + tk * 16384;
#pragma unroll
    for (int l = 0; l < 8; l++) {
      const int row = l * 8 + krow;
      const int chg = (kch & 16) | ((kch ^ row) & 15);
      gl_lds16(kbt + row * 256 + chg * 8, &Klds[l * 2048 + tid * 8]);
    }
    const int tm = (t + 4 < 64) ? t + 4 : 63;
#pragma unroll
    for (int l2 = 0; l2 < 2; l2++)
      gl_lds16(mb + (q0 + l2 * 16 + mrow) * 4096 + tm * 64 + mco,
               &Mlds[tm & 3][l2 * 1024 + tid * 4]);

    // ---- V(t) ready: drain everything older (K(t+1)8 + m2 stay) ----
    __asm__ __volatile__("s_waitcnt vmcnt(10)"
        : "+v"(vc[0][0]), "+v"(vc[0][1]), "+v"(vc[0][2]), "+v"(vc[0][3]),
          "+v"(vc[1][0]), "+v"(vc[1][1]), "+v"(vc[1][2]), "+v"(vc[1][3])
        :: "memory");

    // ---- O += P V ; row-sum via ones-frag MFMA ----
#pragma unroll
    for (int k2 = 0; k2 < 2; k2++) {
      bf8 ap[2];
#pragma unroll
      for (int ms = 0; ms < 2; ms++)  // A[m=lane&15][k=quad*8+j]
        ap[ms] = *(const bf8*)&pw[(ms * 16 + c) * 76 + k2 * 32 + quad * 8];
#pragma unroll
      for (int ms = 0; ms < 2; ms++) {
        lacc[ms] = mfma16(ap[ms], ONES, lacc[ms]);
#pragma unroll
        for (int ds = 0; ds < 4; ds++)
          accO[ms][ds] = mfma16(ap[ms], vc[k2][ds], accO[ms][ds]);
      }
    }

    // B1: K(t+1) arrived (leave mask(t+4) in flight); WAR safe for Klds
    __asm__ __volatile__("s_waitcnt vmcnt(2)\ns_barrier" ::: "memory");
  }

  // ---- epilogue: O / l ----
  float* ob = out + (batch * 4096 + q0) * 256;
#pragma unroll
  for (int ms = 0; ms < 2; ms++) {
    f4 rl;
#pragma unroll
    for (int r = 0; r < 4; r++) rl[r] = __builtin_amdgcn_rcpf(lacc[ms][r]);
#pragma unroll
    for (int ds = 0; ds < 4; ds++)
#pragma unroll
      for (int r = 0; r < 4; r++)
        ob[(ms * 16 + quad * 4 + r) * 256 + w * 64 + ds * 16 + c] =
            accO[ms][ds][r] * rl[r];
  }
}

extern "C" void kernel_launch(void* const* d_in, const int* in_sizes, int n_in,
                              void* d_out, int out_size, void* d_ws, size_t ws_size,
                              hipStream_t stream) {
  const float* x = (const float*)d_in[0];
  const int* mask = (const int*)d_in[1];
  const float* Wq = (const float*)d_in[2];
  const float* bq = (const float*)d_in[3];
  const float* Wk = (const float*)d_in[4];
  const float* bk = (const float*)d_in[5];
  const float* Wv = (const float*)d_in[6];
  const float* bv = (const float*)d_in[7];
  float* out = (float*)d_out;

  char* ws = (char*)d_ws;  // 24 MiB
  short* Qs = (short*)ws;
  short* Kb = (short*)(ws + (8u << 20));
  short* Vt = (short*)(ws + (16u << 20));

  qkv<<<dim3(256, 3), 256, 0, stream>>>(x, Wq, Wk, Wv, bq, bk, bv, Qs, Kb, Vt);
  flash<<<512, 256, 0, stream>>>(Qs, Kb, Vt, mask, out);
}